// Round 11
// baseline (30775.171 us; speedup 1.0000x reference)
//
#include <hip/hip_runtime.h>
#include <math.h>

#define T_STEPS 2048
#define B_SZ 32
#define F_SZ 512
#define H_SZ 512
#define H4_SZ 2048
#define NC_SZ 64
#define NBLK 64
#define RINGE 16384          // fp16 elems per ring slot (32 KB), fragment-ordered
#define FLAG_STRIDE 32       // u32s -> 128 B: one LLC line per block's flag

typedef _Float16 f16x8 __attribute__((ext_vector_type(8)));
typedef float f32x4 __attribute__((ext_vector_type(4)));

#define TIDX(l, w, rt, ct) (((((l)*4 + (w))*2 + (rt))*2 + (ct)))

// r11 theory (from r10's "polls succeed instantly" + protocol-invariant floor):
// the floor was the EXECUTION time of the sc0sc1-bypass h-load burst itself —
// bypass requests appear to service ~serially per wave (~1us each, 16/wave
// = the 15-17us/iter floor that survived every protocol change). Fix: after
// the flag poll, ONE agent-acquire fence (s_waitcnt + bulk buffer_inv of
// L1+L2), then PLAIN CACHED dwordx4 loads: they miss invalidated L2, hit
// LLC, and PIPELINE through normal MSHRs (one latency + transfer for 8KB).
// Correctness: producers write-through to LLC (sc0sc1 stores) + vmcnt drain
// BEFORE flag; consumer sees flag -> fence invalidates stale L1/L2 -> cached
// loads must refill from LLC -> fresh data. Same visibility argument as
// r6-r8 (validated), only the consumer's fetch path changed.
#define LDFRAG16(d, a0, a1, a2, a3)                                             \
  asm volatile(                                                                 \
    "global_load_dwordx4 %0, %16, off\n\t"                                      \
    "global_load_dwordx4 %1, %16, off offset:1024\n\t"                          \
    "global_load_dwordx4 %2, %16, off offset:2048\n\t"                          \
    "global_load_dwordx4 %3, %16, off offset:3072\n\t"                          \
    "global_load_dwordx4 %4, %17, off\n\t"                                      \
    "global_load_dwordx4 %5, %17, off offset:1024\n\t"                          \
    "global_load_dwordx4 %6, %17, off offset:2048\n\t"                          \
    "global_load_dwordx4 %7, %17, off offset:3072\n\t"                          \
    "global_load_dwordx4 %8, %18, off\n\t"                                      \
    "global_load_dwordx4 %9, %18, off offset:1024\n\t"                          \
    "global_load_dwordx4 %10, %18, off offset:2048\n\t"                         \
    "global_load_dwordx4 %11, %18, off offset:3072\n\t"                         \
    "global_load_dwordx4 %12, %19, off\n\t"                                     \
    "global_load_dwordx4 %13, %19, off offset:1024\n\t"                         \
    "global_load_dwordx4 %14, %19, off offset:2048\n\t"                         \
    "global_load_dwordx4 %15, %19, off offset:3072\n\t"                         \
    "s_waitcnt vmcnt(0)"                                                        \
    : "=&v"(d[0][0]), "=&v"(d[1][0]), "=&v"(d[0][1]), "=&v"(d[1][1]),           \
      "=&v"(d[0][2]), "=&v"(d[1][2]), "=&v"(d[0][3]), "=&v"(d[1][3]),           \
      "=&v"(d[0][4]), "=&v"(d[1][4]), "=&v"(d[0][5]), "=&v"(d[1][5]),           \
      "=&v"(d[0][6]), "=&v"(d[1][6]), "=&v"(d[0][7]), "=&v"(d[1][7])            \
    : "v"(a0), "v"(a1), "v"(a2), "v"(a3)                                        \
    : "memory")

// Persistent 2-layer LSTM (r8 structure; only the consumer load path changed).
// 64 blocks x 256 thr. Block j owns hidden units [8j,8j+8) of BOTH layers
// (c-state in regs). Iter it: layer0 t=it, layer1 t=it-1, one flag-barrier.
__global__ __launch_bounds__(256, 1) void lstm_persistent(
    const float* __restrict__ feats,
    const float* __restrict__ Wi0, const float* __restrict__ Wh0,
    const float* __restrict__ bh0,
    const float* __restrict__ Wi1, const float* __restrict__ Wh1,
    const float* __restrict__ bh1,
    const float* __restrict__ Wout, const float* __restrict__ bout,
    float* __restrict__ out,
    _Float16* __restrict__ h0ring,  // [2][RINGE] fp16, fragment-ordered
    _Float16* __restrict__ h1ring,  // [2][RINGE] fp16, fragment-ordered
    float* __restrict__ h1fin,      // [32][512] f32 final h1
    unsigned* __restrict__ flags)   // [64 * FLAG_STRIDE] per-block flags, padded
{
    const int tid   = threadIdx.x;
    const int lane  = tid & 63;
    const int wv    = tid >> 6;          // wave 0..3 = K-quarter of stacked K=1024
    const int jb    = blockIdx.x;        // 0..63
    const int hbase = jb * 8;
    const int rlane = lane & 15;
    const int klo   = (lane >> 4) * 8;

    __shared__ float zs[32 * 272];       // 32 tiles of 16x17 f32 partials
    __shared__ float ps[256];

    // ---- one-time: weight fragments (fp16) ----
    // layer0 stacked K: [Wi0(512); Wh0(512)], A0 = [x | h0]
    // layer1 stacked K: [Wh1(512); Wi1(512)], A1 = [h1 | h0]
    // B frag 16x16x32: lane holds col=lane&15, k=(lane>>4)*8+i  (verified r1)
    f16x8 wf0[2][8], wf1[2][8];
    #pragma unroll
    for (int ct = 0; ct < 2; ++ct) {
        const int cc   = ct * 16 + rlane;
        const int jcol = (cc >> 3) * H_SZ + hbase + (cc & 7);
        #pragma unroll
        for (int ks = 0; ks < 8; ++ks) {
            const int k0 = 256 * wv + 32 * ks + klo;
            f16x8 f0, f1;
            #pragma unroll
            for (int i = 0; i < 8; ++i) {
                const int k = k0 + i;
                const float v0 = (k < H_SZ) ? Wi0[(size_t)k * H4_SZ + jcol]
                                            : Wh0[(size_t)(k - H_SZ) * H4_SZ + jcol];
                const float v1 = (k < H_SZ) ? Wh1[(size_t)k * H4_SZ + jcol]
                                            : Wi1[(size_t)(k - H_SZ) * H4_SZ + jcol];
                f0[i] = (_Float16)v0;
                f1[i] = (_Float16)v1;
            }
            wf0[ct][ks] = f0;
            wf1[ct][ks] = f1;
        }
    }

    // gate-thread mapping: all 256 threads, one (batch,unit) each
    const int gb = tid >> 3, gu = tid & 7;
    const int grow = gb & 15, grt = gb >> 4;
    float c0 = 0.f, c1 = 0.f;
    float bias0[4], bias1[4];
    #pragma unroll
    for (int g = 0; g < 4; ++g) {
        bias0[g] = bh0[g * H_SZ + hbase + gu];
        bias1[g] = bh1[g * H_SZ + hbase + gu];
    }
    // producer scatter index into fragment-ordered ring for value (b=gb,
    // u=hbase+gu): kql=jb>>5, ks=(jb>>2)&7, lane=(jb&3)*16+(gb&15), rt=gb>>4
    const int eidx = (jb >> 5) * 8192
                   + ((((jb >> 2) & 7) * 2) + (gb >> 4)) * 512
                   + ((jb & 3) * 16 + (gb & 15)) * 8 + gu;

    f16x8 xf[2][8];   // prefetched+converted x fragments (waves 0,1)

#define PREFETCH_X(tt_) do {                                                         \
    if (wv < 2 && (tt_) < T_STEPS) {                                                 \
        _Pragma("unroll")                                                            \
        for (int rt = 0; rt < 2; ++rt) {                                             \
            const float* xr = feats                                                  \
                + ((size_t)(rt * 16 + rlane) * T_STEPS + (size_t)(tt_)) * F_SZ       \
                + 256 * wv + klo;                                                    \
            _Pragma("unroll")                                                        \
            for (int ks = 0; ks < 8; ++ks) {                                         \
                const float4 p0 = *(const float4*)(xr + 32 * ks);                    \
                const float4 p1 = *(const float4*)(xr + 32 * ks + 4);                \
                f16x8 t;                                                             \
                t[0] = (_Float16)p0.x; t[1] = (_Float16)p0.y;                        \
                t[2] = (_Float16)p0.z; t[3] = (_Float16)p0.w;                        \
                t[4] = (_Float16)p1.x; t[5] = (_Float16)p1.y;                        \
                t[6] = (_Float16)p1.z; t[7] = (_Float16)p1.w;                        \
                xf[rt][ks] = t;                                                      \
            }                                                                        \
        }                                                                            \
    }                                                                                \
} while (0)

    PREFETCH_X(0);

    for (int it = 0; it <= T_STEPS; ++it) {
        // ---- distributed barrier: each poll lane owns one padded flag line ----
        if (tid < 64) {
            while (__hip_atomic_load(&flags[(size_t)lane * FLAG_STRIDE],
                                     __ATOMIC_RELAXED, __HIP_MEMORY_SCOPE_AGENT)
                   < (unsigned)it) { }
        }
        __syncthreads();

        // ONE bulk L1+L2 invalidate; subsequent plain loads refill from LLC.
        // (Also waits vmcnt(0): x-prefetch was issued a full phase earlier and
        // is complete by now.)
        __builtin_amdgcn_fence(__ATOMIC_ACQUIRE, "agent");

        // ---- h fragments: plain cached, fully-coalesced, pipelined ----
        // wv>=2: h0[it-1] slot (it+1)&1, kql=wv-2 (shared by layer0 & layer1)
        // wv<2 : h1[it-2] slot it&1,     kql=wv
        f16x8 hA[2][8];
        if (wv >= 2) {
            const _Float16* b = h0ring + (size_t)((it + 1) & 1) * RINGE
                                + (wv - 2) * 8192 + lane * 8;
            LDFRAG16(hA, b, b + 2048, b + 4096, b + 6144);
        } else if (it > 0) {
            const _Float16* b = h1ring + (size_t)(it & 1) * RINGE
                                + wv * 8192 + lane * 8;
            LDFRAG16(hA, b, b + 2048, b + 4096, b + 6144);
        }

        const int r0 = (lane >> 4) * 4, ccl = lane & 15;

        // ---- layer0 MFMA (t=it): A = x (wv<2, in regs) or h0 (wv>=2) ----
        if (it < T_STEPS) {
            f32x4 a00 = {0,0,0,0}, a01 = {0,0,0,0}, a10 = {0,0,0,0}, a11 = {0,0,0,0};
            #pragma unroll
            for (int ks = 0; ks < 8; ++ks) {
                const f16x8 ar0 = (wv < 2) ? xf[0][ks] : hA[0][ks];
                const f16x8 ar1 = (wv < 2) ? xf[1][ks] : hA[1][ks];
                a00 = __builtin_amdgcn_mfma_f32_16x16x32_f16(ar0, wf0[0][ks], a00, 0, 0, 0);
                a01 = __builtin_amdgcn_mfma_f32_16x16x32_f16(ar0, wf0[1][ks], a01, 0, 0, 0);
                a10 = __builtin_amdgcn_mfma_f32_16x16x32_f16(ar1, wf0[0][ks], a10, 0, 0, 0);
                a11 = __builtin_amdgcn_mfma_f32_16x16x32_f16(ar1, wf0[1][ks], a11, 0, 0, 0);
            }
            #pragma unroll
            for (int q = 0; q < 4; ++q) {
                zs[TIDX(0, wv, 0, 0) * 272 + (r0 + q) * 17 + ccl] = a00[q];
                zs[TIDX(0, wv, 0, 1) * 272 + (r0 + q) * 17 + ccl] = a01[q];
                zs[TIDX(0, wv, 1, 0) * 272 + (r0 + q) * 17 + ccl] = a10[q];
                zs[TIDX(0, wv, 1, 1) * 272 + (r0 + q) * 17 + ccl] = a11[q];
            }
        }

        // prefetch x[it+1] here (xf consumed above): completes during layer1 +
        // gates + drain + poll, so the next fence's vmcnt(0) never stalls on it
        PREFETCH_X(it + 1);

        // ---- layer1 MFMA (t=it-1): A = h1 (wv<2) or h0 (wv>=2) = hA ----
        if (it > 0) {
            f32x4 a00 = {0,0,0,0}, a01 = {0,0,0,0}, a10 = {0,0,0,0}, a11 = {0,0,0,0};
            #pragma unroll
            for (int ks = 0; ks < 8; ++ks) {
                a00 = __builtin_amdgcn_mfma_f32_16x16x32_f16(hA[0][ks], wf1[0][ks], a00, 0, 0, 0);
                a01 = __builtin_amdgcn_mfma_f32_16x16x32_f16(hA[0][ks], wf1[1][ks], a01, 0, 0, 0);
                a10 = __builtin_amdgcn_mfma_f32_16x16x32_f16(hA[1][ks], wf1[0][ks], a10, 0, 0, 0);
                a11 = __builtin_amdgcn_mfma_f32_16x16x32_f16(hA[1][ks], wf1[1][ks], a11, 0, 0, 0);
            }
            #pragma unroll
            for (int q = 0; q < 4; ++q) {
                zs[TIDX(1, wv, 0, 0) * 272 + (r0 + q) * 17 + ccl] = a00[q];
                zs[TIDX(1, wv, 0, 1) * 272 + (r0 + q) * 17 + ccl] = a01[q];
                zs[TIDX(1, wv, 1, 0) * 272 + (r0 + q) * 17 + ccl] = a10[q];
                zs[TIDX(1, wv, 1, 1) * 272 + (r0 + q) * 17 + ccl] = a11[q];
            }
        }
        __syncthreads();

        // ---- gates: reduce 4 K-partials, update c, scatter h (sc0sc1 WT) ----
        if (it < T_STEPS) {
            float z[4];
            #pragma unroll
            for (int g = 0; g < 4; ++g) {
                const int cc = g * 8 + gu, ct = cc >> 4, col = cc & 15;
                float v = bias0[g];
                #pragma unroll
                for (int w = 0; w < 4; ++w)
                    v += zs[TIDX(0, w, grt, ct) * 272 + grow * 17 + col];
                z[g] = v;
            }
            const float ig = 1.f / (1.f + expf(-z[0]));
            const float fg = 1.f / (1.f + expf(-z[1]));
            const float gg = tanhf(z[2]);
            const float og = 1.f / (1.f + expf(-z[3]));
            c0 = fg * c0 + ig * gg;
            const float hv = og * tanhf(c0);
            union { _Float16 h; unsigned short s; } cv; cv.h = (_Float16)hv;
            __hip_atomic_store(
                (unsigned short*)(h0ring + (size_t)(it & 1) * RINGE + eidx),
                cv.s, __ATOMIC_RELAXED, __HIP_MEMORY_SCOPE_AGENT);
        }
        if (it > 0) {
            float z[4];
            #pragma unroll
            for (int g = 0; g < 4; ++g) {
                const int cc = g * 8 + gu, ct = cc >> 4, col = cc & 15;
                float v = bias1[g];
                #pragma unroll
                for (int w = 0; w < 4; ++w)
                    v += zs[TIDX(1, w, grt, ct) * 272 + grow * 17 + col];
                z[g] = v;
            }
            const float ig = 1.f / (1.f + expf(-z[0]));
            const float fg = 1.f / (1.f + expf(-z[1]));
            const float gg = tanhf(z[2]);
            const float og = 1.f / (1.f + expf(-z[3]));
            c1 = fg * c1 + ig * gg;
            const float hv = og * tanhf(c1);
            union { _Float16 h; unsigned short s; } cv; cv.h = (_Float16)hv;
            __hip_atomic_store(
                (unsigned short*)(h1ring + (size_t)((it + 1) & 1) * RINGE + eidx),
                cv.s, __ATOMIC_RELAXED, __HIP_MEMORY_SCOPE_AGENT);
            if (it == T_STEPS) {
                union { float f; unsigned u; } cf; cf.f = hv;
                __hip_atomic_store((unsigned*)(h1fin + gb * H_SZ + hbase + gu),
                                   cf.u, __ATOMIC_RELAXED, __HIP_MEMORY_SCOPE_AGENT);
            }
        }
        // drain write-through stores to the LLC, then arrive on own flag line
        asm volatile("s_waitcnt vmcnt(0)" ::: "memory");
        __syncthreads();
        if (tid == 0)
            __hip_atomic_store(&flags[(size_t)jb * FLAG_STRIDE], (unsigned)(it + 1),
                               __ATOMIC_RELAXED, __HIP_MEMORY_SCOPE_AGENT);
    }

    // final barrier: all h1fin stores visible
    if (tid < 64) {
        while (__hip_atomic_load(&flags[(size_t)lane * FLAG_STRIDE],
                                 __ATOMIC_RELAXED, __HIP_MEMORY_SCOPE_AGENT)
               < (unsigned)(T_STEPS + 1)) { }
    }
    __syncthreads();

    // ---- output head: block jb -> out[:, jb] ----
    {
        const int b = tid & 31, kc = tid >> 5;
        float part = 0.f;
        for (int k = kc * 64; k < kc * 64 + 64; ++k) {
            union { unsigned u; float f; } cv;
            cv.u = __hip_atomic_load((const unsigned*)(h1fin + b * H_SZ + k),
                                     __ATOMIC_RELAXED, __HIP_MEMORY_SCOPE_AGENT);
            part += cv.f * Wout[(size_t)k * NC_SZ + jb];
        }
        ps[kc * 32 + b] = part;
        __syncthreads();
        if (tid < 32) {
            float acc = bout[jb];
            #pragma unroll
            for (int c = 0; c < 8; ++c) acc += ps[c * 32 + tid];
            out[tid * NC_SZ + jb] = acc;
        }
    }
#undef PREFETCH_X
}

extern "C" void kernel_launch(void* const* d_in, const int* in_sizes, int n_in,
                              void* d_out, int out_size, void* d_ws, size_t ws_size,
                              hipStream_t stream) {
    const float* feats = (const float*)d_in[0];
    const float* Wi0   = (const float*)d_in[1];
    const float* Wh0   = (const float*)d_in[2];
    const float* bh0   = (const float*)d_in[3];
    const float* Wi1   = (const float*)d_in[4];
    const float* Wh1   = (const float*)d_in[5];
    const float* bh1   = (const float*)d_in[6];
    const float* Wout  = (const float*)d_in[7];
    const float* bout  = (const float*)d_in[8];

    char* ws = (char*)d_ws;
    _Float16* h0ring = (_Float16*)(ws);           // 2 slots * 32 KB
    _Float16* h1ring = (_Float16*)(ws + 131072);  // 2 slots * 32 KB
    float*    h1fin  = (float*)(ws + 262144);     // 64 KB
    unsigned* flags  = (unsigned*)(ws + 327680);  // 64 * 128 B = 8 KB

    // zero rings (h[-1]=h[-2]=0), final buf, flags — every call (determinism;
    // graph replays reuse ws, so stale flags MUST be cleared each call)
    hipMemsetAsync(d_ws, 0, 335872, stream);

    lstm_persistent<<<dim3(NBLK), dim3(256), 0, stream>>>(
        feats, Wi0, Wh0, bh0, Wi1, Wh1, bh1, Wout, bout,
        (float*)d_out, h0ring, h1ring, h1fin, flags);
}